// Round 1
// baseline (545.399 us; speedup 1.0000x reference)
//
#include <hip/hip_runtime.h>
#include <math.h>

#define Bb 8
#define Cc 512
#define Nn 4096
#define Mm 64
#define OC 640            // M + M + C
#define EPSf 1e-6f

// ---------------- workspace layout (floats) ----------------
constexpr size_t OFF_GATE = 0;                                // [B][C]
constexpr size_t OFF_WCAT = OFF_GATE + (size_t)Bb * Cc;       // [OC][C]
constexpr size_t OFF_BCAT = OFF_WCAT + (size_t)OC * Cc;       // [OC]
constexpr size_t OFF_QF   = OFF_BCAT + (size_t)OC;            // [B][M][N]
constexpr size_t OFF_KF   = OFF_QF + (size_t)Bb * Mm * Nn;    // [B][M][N]
constexpr size_t OFF_V    = OFF_KF + (size_t)Bb * Mm * Nn;    // [B][C][N]
constexpr size_t OFF_KV   = OFF_V + (size_t)Bb * Cc * Nn;     // [B][M][C]
constexpr size_t OFF_KSUM = OFF_KV + (size_t)Bb * Mm * Cc;    // [B][M]
constexpr size_t OFF_NORM = OFF_KSUM + (size_t)Bb * Mm;       // [B][N]

__device__ __forceinline__ float softplus_f(float v) {
    return (v > 20.f) ? v : log1pf(expf(v));
}

// ---------------- concat weights into Wcat/bcat ----------------
__global__ void concat_w_k(const float* __restrict__ wq, const float* __restrict__ bq,
                           const float* __restrict__ wk, const float* __restrict__ bk,
                           const float* __restrict__ wv, const float* __restrict__ bv,
                           float* __restrict__ Wcat, float* __restrict__ bcat) {
    int i = blockIdx.x * 256 + threadIdx.x;
    if (i < OC * Cc) {
        int o = i / Cc, c = i % Cc;
        float v;
        if (o < Mm)            v = wq[o * Cc + c];
        else if (o < 2 * Mm)   v = wk[(o - Mm) * Cc + c];
        else                   v = wv[(o - 2 * Mm) * Cc + c];
        Wcat[i] = v;
    }
    if (i < OC) {
        float v;
        if (i < Mm)            v = bq[i];
        else if (i < 2 * Mm)   v = bk[i - Mm];
        else                   v = bv[i - 2 * Mm];
        bcat[i] = v;
    }
}

// ---------------- gate[b][c] = max_n x + mean_n x ----------------
__global__ __launch_bounds__(256) void gate_k(const float* __restrict__ x, float* __restrict__ gate) {
    int bc = blockIdx.x;
    const float* row = x + (size_t)bc * Nn;
    int t = threadIdx.x;
    float mx = -3.4e38f, sm = 0.f;
    for (int i = t * 4; i < Nn; i += 256 * 4) {
        float4 v = *(const float4*)(row + i);
        mx = fmaxf(mx, fmaxf(fmaxf(v.x, v.y), fmaxf(v.z, v.w)));
        sm += v.x + v.y + v.z + v.w;
    }
    #pragma unroll
    for (int off = 32; off; off >>= 1) {
        mx = fmaxf(mx, __shfl_xor(mx, off));
        sm += __shfl_xor(sm, off);
    }
    __shared__ float smx[4], ssm[4];
    int wid = t >> 6;
    if ((t & 63) == 0) { smx[wid] = mx; ssm[wid] = sm; }
    __syncthreads();
    if (t == 0) {
        mx = fmaxf(fmaxf(smx[0], smx[1]), fmaxf(smx[2], smx[3]));
        sm = ssm[0] + ssm[1] + ssm[2] + ssm[3];
        gate[bc] = mx + sm * (1.f / Nn);
    }
}

// ---------------- fused QKV channel-GEMM ----------------
// Out[b, o, n] = sum_c Wcat[o,c] * x[b,c,n] + bcat[o]; epilogue per type.
// grid: (N/64, OC/64, B), block 256. Tile 64x64, BK=16, 4x4 per thread.
__global__ __launch_bounds__(256) void qkv_k(const float* __restrict__ x,
                                             const float* __restrict__ Wcat,
                                             const float* __restrict__ bcat,
                                             const float* __restrict__ gate,
                                             float* __restrict__ Qf,
                                             float* __restrict__ Kf,
                                             float* __restrict__ Vv) {
    const int nb = blockIdx.x * 64;
    const int ob = blockIdx.y * 64;
    const int b  = blockIdx.z;
    __shared__ float Wt[16][65];   // [k][o]
    __shared__ float Xt[16][65];   // [k][n]
    const int tid = threadIdx.x;
    const int tr = tid >> 4, tc = tid & 15;
    float acc[4][4] = {};
    const float* xb = x + (size_t)b * Cc * Nn;

    for (int kb = 0; kb < Cc; kb += 16) {
        #pragma unroll
        for (int r = 0; r < 4; r++) {
            int o = (tid >> 4) + r * 16;
            int k = tid & 15;
            Wt[k][o] = Wcat[(size_t)(ob + o) * Cc + kb + k];
        }
        #pragma unroll
        for (int r = 0; r < 4; r++) {
            int k = (tid >> 6) + r * 4;
            int n = tid & 63;
            Xt[k][n] = xb[(size_t)(kb + k) * Nn + nb + n];
        }
        __syncthreads();
        #pragma unroll
        for (int k = 0; k < 16; k++) {
            float a0 = Wt[k][tr * 4 + 0], a1 = Wt[k][tr * 4 + 1];
            float a2 = Wt[k][tr * 4 + 2], a3 = Wt[k][tr * 4 + 3];
            float b0 = Xt[k][tc * 4 + 0], b1 = Xt[k][tc * 4 + 1];
            float b2 = Xt[k][tc * 4 + 2], b3 = Xt[k][tc * 4 + 3];
            acc[0][0] += a0 * b0; acc[0][1] += a0 * b1; acc[0][2] += a0 * b2; acc[0][3] += a0 * b3;
            acc[1][0] += a1 * b0; acc[1][1] += a1 * b1; acc[1][2] += a1 * b2; acc[1][3] += a1 * b3;
            acc[2][0] += a2 * b0; acc[2][1] += a2 * b1; acc[2][2] += a2 * b2; acc[2][3] += a2 * b3;
            acc[3][0] += a3 * b0; acc[3][1] += a3 * b1; acc[3][2] += a3 * b2; acc[3][3] += a3 * b3;
        }
        __syncthreads();
    }

    const int otype = (ob < 64) ? 0 : (ob < 128) ? 1 : 2;  // uniform per block
    #pragma unroll
    for (int i = 0; i < 4; i++) {
        int o = ob + tr * 4 + i;
        float bias = bcat[o];
        float4 v;
        v.x = acc[i][0] + bias; v.y = acc[i][1] + bias;
        v.z = acc[i][2] + bias; v.w = acc[i][3] + bias;
        int n0 = nb + tc * 4;
        if (otype == 0) {
            v.x = softplus_f(v.x); v.y = softplus_f(v.y); v.z = softplus_f(v.z); v.w = softplus_f(v.w);
            *(float4*)(Qf + ((size_t)b * Mm + o) * Nn + n0) = v;
        } else if (otype == 1) {
            v.x = softplus_f(v.x); v.y = softplus_f(v.y); v.z = softplus_f(v.z); v.w = softplus_f(v.w);
            *(float4*)(Kf + ((size_t)b * Mm + (o - 64)) * Nn + n0) = v;
        } else {
            int c = o - 128;
            float g = gate[b * Cc + c];
            v.x *= g; v.y *= g; v.z *= g; v.w *= g;
            *(float4*)(Vv + ((size_t)b * Cc + c) * Nn + n0) = v;
        }
    }
}

// ---------------- Ksum[b][m] = sum_n Kf ----------------
__global__ __launch_bounds__(256) void ksum_k(const float* __restrict__ Kf, float* __restrict__ Ksum) {
    int bm = blockIdx.x;
    const float* row = Kf + (size_t)bm * Nn;
    int t = threadIdx.x;
    float sm = 0.f;
    for (int i = t * 4; i < Nn; i += 1024) {
        float4 v = *(const float4*)(row + i);
        sm += v.x + v.y + v.z + v.w;
    }
    #pragma unroll
    for (int off = 32; off; off >>= 1) sm += __shfl_xor(sm, off);
    __shared__ float ssm[4];
    if ((t & 63) == 0) ssm[t >> 6] = sm;
    __syncthreads();
    if (t == 0) Ksum[bm] = ssm[0] + ssm[1] + ssm[2] + ssm[3];
}

// ---------------- KV[b][m][c] = sum_n Kf[b,m,n] * V[b,c,n] ----------------
// grid: (C/64, N/512, B), block 256; split-N with atomics. 4x4 per thread over (m,c).
__global__ __launch_bounds__(256) void kv_k(const float* __restrict__ Kf,
                                            const float* __restrict__ Vv,
                                            float* __restrict__ KV) {
    const int cb = blockIdx.x * 64;
    const int n0 = blockIdx.y * 512;
    const int b  = blockIdx.z;
    __shared__ float Kt[64][65];   // [m][n]
    __shared__ float Vt[64][65];   // [c][n]
    const int tid = threadIdx.x;
    const int tr = tid >> 4, tc = tid & 15;
    float acc[4][4] = {};

    for (int ns = 0; ns < 512; ns += 64) {
        #pragma unroll
        for (int r = 0; r < 16; r++) {
            int m = (tid >> 6) + r * 4;
            int n = tid & 63;
            Kt[m][n] = Kf[((size_t)b * Mm + m) * Nn + n0 + ns + n];
            Vt[m][n] = Vv[((size_t)b * Cc + cb + m) * Nn + n0 + ns + n];
        }
        __syncthreads();
        #pragma unroll 8
        for (int k = 0; k < 64; k++) {
            float a0 = Kt[tr * 4 + 0][k], a1 = Kt[tr * 4 + 1][k];
            float a2 = Kt[tr * 4 + 2][k], a3 = Kt[tr * 4 + 3][k];
            float b0 = Vt[tc * 4 + 0][k], b1 = Vt[tc * 4 + 1][k];
            float b2 = Vt[tc * 4 + 2][k], b3 = Vt[tc * 4 + 3][k];
            acc[0][0] += a0 * b0; acc[0][1] += a0 * b1; acc[0][2] += a0 * b2; acc[0][3] += a0 * b3;
            acc[1][0] += a1 * b0; acc[1][1] += a1 * b1; acc[1][2] += a1 * b2; acc[1][3] += a1 * b3;
            acc[2][0] += a2 * b0; acc[2][1] += a2 * b1; acc[2][2] += a2 * b2; acc[2][3] += a2 * b3;
            acc[3][0] += a3 * b0; acc[3][1] += a3 * b1; acc[3][2] += a3 * b2; acc[3][3] += a3 * b3;
        }
        __syncthreads();
    }
    #pragma unroll
    for (int i = 0; i < 4; i++)
        #pragma unroll
        for (int j = 0; j < 4; j++)
            atomicAdd(&KV[((size_t)b * Mm + tr * 4 + i) * Cc + cb + tc * 4 + j], acc[i][j]);
}

// ---------------- norm[b][n] = 1 / sum_m Qf[b,m,n]*(Ksum[b,m]+EPS) ----------------
__global__ __launch_bounds__(256) void norm_k(const float* __restrict__ Qf,
                                              const float* __restrict__ Ksum,
                                              float* __restrict__ normb) {
    int b = blockIdx.y;
    int n = blockIdx.x * 256 + threadIdx.x;
    __shared__ float ks[Mm];
    if (threadIdx.x < Mm) ks[threadIdx.x] = Ksum[b * Mm + threadIdx.x] + EPSf;
    __syncthreads();
    float s = 0.f;
    #pragma unroll 8
    for (int m = 0; m < Mm; m++) s += Qf[((size_t)b * Mm + m) * Nn + n] * ks[m];
    normb[(size_t)b * Nn + n] = 1.f / s;
}

// ---------------- out[b,c,n] = x + gamma * norm[b,n] * sum_m Qf[b,m,n]*KV[b,m,c] ----------------
// grid: (N/64, C/64, B), block 256. K-dim = M = 64, single LDS stage.
__global__ __launch_bounds__(256) void final_k(const float* __restrict__ x,
                                               const float* __restrict__ Qf,
                                               const float* __restrict__ KV,
                                               const float* __restrict__ normb,
                                               const float* __restrict__ gamma,
                                               float* __restrict__ out) {
    const int nb = blockIdx.x * 64;
    const int cb = blockIdx.y * 64;
    const int b  = blockIdx.z;
    __shared__ float Qt[64][65];    // [m][n]
    __shared__ float KVt[64][65];   // [m][c]
    const int tid = threadIdx.x;
    const int tr = tid >> 4, tc = tid & 15;

    #pragma unroll
    for (int r = 0; r < 16; r++) {
        int m = (tid >> 6) + r * 4;
        int n = tid & 63;
        Qt[m][n]  = Qf[((size_t)b * Mm + m) * Nn + nb + n];
        KVt[m][n] = KV[((size_t)b * Mm + m) * Cc + cb + n];
    }
    __syncthreads();
    float acc[4][4] = {};
    #pragma unroll 8
    for (int k = 0; k < 64; k++) {
        float a0 = KVt[k][tr * 4 + 0], a1 = KVt[k][tr * 4 + 1];
        float a2 = KVt[k][tr * 4 + 2], a3 = KVt[k][tr * 4 + 3];
        float b0 = Qt[k][tc * 4 + 0], b1 = Qt[k][tc * 4 + 1];
        float b2 = Qt[k][tc * 4 + 2], b3 = Qt[k][tc * 4 + 3];
        acc[0][0] += a0 * b0; acc[0][1] += a0 * b1; acc[0][2] += a0 * b2; acc[0][3] += a0 * b3;
        acc[1][0] += a1 * b0; acc[1][1] += a1 * b1; acc[1][2] += a1 * b2; acc[1][3] += a1 * b3;
        acc[2][0] += a2 * b0; acc[2][1] += a2 * b1; acc[2][2] += a2 * b2; acc[2][3] += a2 * b3;
        acc[3][0] += a3 * b0; acc[3][1] += a3 * b1; acc[3][2] += a3 * b2; acc[3][3] += a3 * b3;
    }
    const float g = gamma[0];
    const int n0 = nb + tc * 4;
    float4 nrm = *(const float4*)(normb + (size_t)b * Nn + n0);
    #pragma unroll
    for (int i = 0; i < 4; i++) {
        int c = cb + tr * 4 + i;
        size_t idx = ((size_t)b * Cc + c) * Nn + n0;
        float4 xv = *(const float4*)(x + idx);
        float4 o;
        o.x = xv.x + g * nrm.x * acc[i][0];
        o.y = xv.y + g * nrm.y * acc[i][1];
        o.z = xv.z + g * nrm.z * acc[i][2];
        o.w = xv.w + g * nrm.w * acc[i][3];
        *(float4*)(out + idx) = o;
    }
}

extern "C" void kernel_launch(void* const* d_in, const int* in_sizes, int n_in,
                              void* d_out, int out_size, void* d_ws, size_t ws_size,
                              hipStream_t stream) {
    const float* x     = (const float*)d_in[0];
    const float* wq    = (const float*)d_in[1];
    const float* bq    = (const float*)d_in[2];
    const float* wk    = (const float*)d_in[3];
    const float* bk    = (const float*)d_in[4];
    const float* wv    = (const float*)d_in[5];
    const float* bv    = (const float*)d_in[6];
    const float* gamma = (const float*)d_in[7];
    float* out = (float*)d_out;
    float* ws  = (float*)d_ws;

    float* gate  = ws + OFF_GATE;
    float* Wcat  = ws + OFF_WCAT;
    float* bcat  = ws + OFF_BCAT;
    float* Qf    = ws + OFF_QF;
    float* Kf    = ws + OFF_KF;
    float* Vv    = ws + OFF_V;
    float* KV    = ws + OFF_KV;
    float* Ksum  = ws + OFF_KSUM;
    float* normb = ws + OFF_NORM;

    concat_w_k<<<(OC * Cc + 255) / 256, 256, 0, stream>>>(wq, bq, wk, bk, wv, bv, Wcat, bcat);
    gate_k<<<Bb * Cc, 256, 0, stream>>>(x, gate);
    qkv_k<<<dim3(Nn / 64, OC / 64, Bb), 256, 0, stream>>>(x, Wcat, bcat, gate, Qf, Kf, Vv);
    ksum_k<<<Bb * Mm, 256, 0, stream>>>(Kf, Ksum);
    hipMemsetAsync(KV, 0, (size_t)Bb * Mm * Cc * sizeof(float), stream);
    kv_k<<<dim3(Cc / 64, Nn / 512, Bb), 256, 0, stream>>>(Kf, Vv, KV);
    norm_k<<<dim3(Nn / 256, Bb), 256, 0, stream>>>(Qf, Ksum, normb);
    final_k<<<dim3(Nn / 64, Cc / 64, Bb), 256, 0, stream>>>(x, Qf, KV, normb, gamma, out);
}

// Round 2
// 226.696 us; speedup vs baseline: 2.4059x; 2.4059x over previous
//
#include <hip/hip_runtime.h>
#include <math.h>

#define Bb 8
#define Cc 512
#define Nn 4096
#define Mm 64
#define OC 640            // M + M + C
#define EPSf 1e-6f

typedef unsigned short ushort_t;
typedef unsigned int uint_t;
typedef __attribute__((ext_vector_type(8))) short short8;
typedef __attribute__((ext_vector_type(4))) float f32x4;

// ---------------- workspace layout (float slots) ----------------
constexpr size_t OFF_GATE = 0;                                   // [B][C] f32
constexpr size_t OFF_BCAT = OFF_GATE + (size_t)Bb * Cc;          // [OC] f32
constexpr size_t OFF_WBF  = OFF_BCAT + (size_t)OC;               // [OC][C] bf16 -> OC*C/2 floats
constexpr size_t OFF_XT   = OFF_WBF + (size_t)OC * Cc / 2;       // [B][N][C] bf16 -> B*N*C/2 floats
constexpr size_t OFF_QF   = OFF_XT + (size_t)Bb * Nn * Cc / 2;   // [B][M][N] f32
constexpr size_t OFF_KF   = OFF_QF + (size_t)Bb * Mm * Nn;       // [B][M][N] f32
constexpr size_t OFF_VBF  = OFF_KF + (size_t)Bb * Mm * Nn;       // [B][C][N] bf16 -> B*C*N/2 floats
constexpr size_t OFF_KV   = OFF_VBF + (size_t)Bb * Cc * Nn / 2;  // [B][M][C] f32
constexpr size_t OFF_KSUM = OFF_KV + (size_t)Bb * Mm * Cc;       // [B][M]
constexpr size_t OFF_NORM = OFF_KSUM + (size_t)Bb * Mm;          // [B][N]

__device__ __forceinline__ float softplus_f(float v) {
    return (v > 20.f) ? v : log1pf(expf(v));
}
__device__ __forceinline__ ushort_t f2bf(float f) {
    uint_t u = __float_as_uint(f);
    uint_t r = (u + 0x7fffu + ((u >> 16) & 1u)) >> 16;
    return (ushort_t)r;
}
__device__ __forceinline__ float bf2f(ushort_t h) {
    return __uint_as_float(((uint_t)h) << 16);
}
__device__ __forceinline__ void gload_lds16(const void* g, void* l) {
    __builtin_amdgcn_global_load_lds(
        (const __attribute__((address_space(1))) unsigned int*)g,
        (__attribute__((address_space(3))) unsigned int*)l, 16, 0, 0);
}

// ---------------- weight concat + bf16 convert ----------------
__global__ void wconv_k(const float* __restrict__ wq, const float* __restrict__ bq,
                        const float* __restrict__ wk, const float* __restrict__ bk,
                        const float* __restrict__ wv, const float* __restrict__ bv,
                        ushort_t* __restrict__ wbf, float* __restrict__ bcat) {
    int i = blockIdx.x * 256 + threadIdx.x;
    if (i < OC * Cc) {
        int o = i / Cc, c = i % Cc;
        float v;
        if (o < Mm)            v = wq[o * Cc + c];
        else if (o < 2 * Mm)   v = wk[(o - Mm) * Cc + c];
        else                   v = wv[(o - 2 * Mm) * Cc + c];
        wbf[i] = f2bf(v);
    }
    if (i < OC) {
        float v;
        if (i < Mm)            v = bq[i];
        else if (i < 2 * Mm)   v = bk[i - Mm];
        else                   v = bv[i - 2 * Mm];
        bcat[i] = v;
    }
}

// ---------------- transpose+convert: xT[b][n][c] = bf16(x[b][c][n]) ----------------
// grid: (N/64, C/64, B), block 256
__global__ __launch_bounds__(256) void xtrans_k(const float* __restrict__ x, ushort_t* __restrict__ xT) {
    const int nb = blockIdx.x * 64;
    const int cb = blockIdx.y * 64;
    const int b  = blockIdx.z;
    __shared__ float Xt[64][65];
    const int t = threadIdx.x;
    #pragma unroll
    for (int r = 0; r < 16; r++) {
        int cl = (t >> 6) + r * 4;
        int nl = t & 63;
        Xt[cl][nl] = x[((size_t)b * Cc + cb + cl) * Nn + nb + nl];
    }
    __syncthreads();
    #pragma unroll
    for (int r = 0; r < 8; r++) {
        int nl = (t >> 5) + r * 8;
        int c0 = (t & 31) * 2;
        uint_t pk = (uint_t)f2bf(Xt[c0][nl]) | ((uint_t)f2bf(Xt[c0 + 1][nl]) << 16);
        *(uint_t*)(xT + ((size_t)b * Nn + nb + nl) * Cc + cb + c0) = pk;
    }
}

// ---------------- gate[b][c] = max_n x + mean_n x ----------------
__global__ __launch_bounds__(256) void gate_k(const float* __restrict__ x, float* __restrict__ gate) {
    int bc = blockIdx.x;
    const float* row = x + (size_t)bc * Nn;
    int t = threadIdx.x;
    float mx = -3.4e38f, sm = 0.f;
    for (int i = t * 4; i < Nn; i += 256 * 4) {
        float4 v = *(const float4*)(row + i);
        mx = fmaxf(mx, fmaxf(fmaxf(v.x, v.y), fmaxf(v.z, v.w)));
        sm += v.x + v.y + v.z + v.w;
    }
    #pragma unroll
    for (int off = 32; off; off >>= 1) {
        mx = fmaxf(mx, __shfl_xor(mx, off));
        sm += __shfl_xor(sm, off);
    }
    __shared__ float smx[4], ssm[4];
    int wid = t >> 6;
    if ((t & 63) == 0) { smx[wid] = mx; ssm[wid] = sm; }
    __syncthreads();
    if (t == 0) {
        mx = fmaxf(fmaxf(smx[0], smx[1]), fmaxf(smx[2], smx[3]));
        sm = ssm[0] + ssm[1] + ssm[2] + ssm[3];
        gate[bc] = mx + sm * (1.f / Nn);
    }
}

// ---------------- fused QKV GEMM via MFMA bf16 ----------------
// D[o,n] = sum_c wbf[o,c] * xT[b,n,c]; both operands K-contiguous.
// grid: (N/128, OC/128, B), block 256 (4 waves, 2x2 of 64x64 sub-tiles), BK=32.
__global__ __launch_bounds__(256) void qkv_mfma_k(const ushort_t* __restrict__ wbf,
                                                  const ushort_t* __restrict__ xT,
                                                  const float* __restrict__ bcat,
                                                  const float* __restrict__ gate,
                                                  float* __restrict__ Qf,
                                                  float* __restrict__ Kf,
                                                  ushort_t* __restrict__ Vbf) {
    const int nb = blockIdx.x * 128;
    const int ob = blockIdx.y * 128;
    const int b  = blockIdx.z;
    __shared__ ushort_t At[128 * 32];   // [o-row][k] linear
    __shared__ ushort_t Bt[128 * 32];   // [n-row][k] linear
    const int tid  = threadIdx.x;
    const int w    = tid >> 6;
    const int lane = tid & 63;
    const int wr   = w >> 1, wc = w & 1;
    const int hi   = lane >> 4, lo = lane & 15;

    f32x4 acc[4][4] = {};
    const ushort_t* xb = xT + (size_t)b * Nn * Cc;

    for (int kb = 0; kb < Cc; kb += 32) {
        #pragma unroll
        for (int li = 0; li < 2; li++) {
            const int rw = (w * 2 + li) * 16 + (lane >> 2);
            const int kc = (lane & 3) * 8;
            gload_lds16(wbf + (size_t)(ob + rw) * Cc + kb + kc, At + (w * 2 + li) * 512);
            gload_lds16(xb + (size_t)(nb + rw) * Cc + kb + kc, Bt + (w * 2 + li) * 512);
        }
        __syncthreads();
        short8 a[4], bfr[4];
        #pragma unroll
        for (int mi = 0; mi < 4; mi++)
            a[mi] = *(const short8*)(At + (wr * 64 + mi * 16 + lo) * 32 + hi * 8);
        #pragma unroll
        for (int ni = 0; ni < 4; ni++)
            bfr[ni] = *(const short8*)(Bt + (wc * 64 + ni * 16 + lo) * 32 + hi * 8);
        #pragma unroll
        for (int mi = 0; mi < 4; mi++)
            #pragma unroll
            for (int ni = 0; ni < 4; ni++)
                acc[mi][ni] = __builtin_amdgcn_mfma_f32_16x16x32_bf16(a[mi], bfr[ni], acc[mi][ni], 0, 0, 0);
        __syncthreads();
    }

    #pragma unroll
    for (int mi = 0; mi < 4; mi++) {
        #pragma unroll
        for (int r = 0; r < 4; r++) {
            const int o = ob + wr * 64 + mi * 16 + hi * 4 + r;
            const float bias = bcat[o];
            if (o < 2 * Mm) {
                float* dst = (o < Mm) ? (Qf + ((size_t)b * Mm + o) * Nn)
                                      : (Kf + ((size_t)b * Mm + (o - Mm)) * Nn);
                #pragma unroll
                for (int ni = 0; ni < 4; ni++) {
                    int n = nb + wc * 64 + ni * 16 + lo;
                    dst[n] = softplus_f(acc[mi][ni][r] + bias);
                }
            } else {
                const int c = o - 2 * Mm;
                const float g = gate[b * Cc + c];
                ushort_t* dst = Vbf + ((size_t)b * Cc + c) * Nn;
                #pragma unroll
                for (int ni = 0; ni < 4; ni++) {
                    int n = nb + wc * 64 + ni * 16 + lo;
                    dst[n] = f2bf(g * (acc[mi][ni][r] + bias));
                }
            }
        }
    }
}

// ---------------- Ksum[b][m] = sum_n Kf ----------------
__global__ __launch_bounds__(256) void ksum_k(const float* __restrict__ Kf, float* __restrict__ Ksum) {
    int bm = blockIdx.x;
    const float* row = Kf + (size_t)bm * Nn;
    int t = threadIdx.x;
    float sm = 0.f;
    for (int i = t * 4; i < Nn; i += 1024) {
        float4 v = *(const float4*)(row + i);
        sm += v.x + v.y + v.z + v.w;
    }
    #pragma unroll
    for (int off = 32; off; off >>= 1) sm += __shfl_xor(sm, off);
    __shared__ float ssm[4];
    if ((t & 63) == 0) ssm[t >> 6] = sm;
    __syncthreads();
    if (t == 0) Ksum[bm] = ssm[0] + ssm[1] + ssm[2] + ssm[3];
}

// ---------------- KV[b][m][c] = sum_n Kf[b,m,n] * V[b,c,n] ----------------
__global__ __launch_bounds__(256) void kv_k(const float* __restrict__ Kf,
                                            const ushort_t* __restrict__ Vbf,
                                            float* __restrict__ KV) {
    const int cb = blockIdx.x * 64;
    const int n0 = blockIdx.y * 512;
    const int b  = blockIdx.z;
    __shared__ float Kt[64][65];   // [m][n]
    __shared__ float Vt[64][65];   // [c][n]
    const int tid = threadIdx.x;
    const int tr = tid >> 4, tc = tid & 15;
    float acc[4][4] = {};

    for (int ns = 0; ns < 512; ns += 64) {
        #pragma unroll
        for (int r = 0; r < 16; r++) {
            int m = (tid >> 6) + r * 4;
            int n = tid & 63;
            Kt[m][n] = Kf[((size_t)b * Mm + m) * Nn + n0 + ns + n];
            Vt[m][n] = bf2f(Vbf[((size_t)b * Cc + cb + m) * Nn + n0 + ns + n]);
        }
        __syncthreads();
        #pragma unroll 8
        for (int k = 0; k < 64; k++) {
            float a0 = Kt[tr * 4 + 0][k], a1 = Kt[tr * 4 + 1][k];
            float a2 = Kt[tr * 4 + 2][k], a3 = Kt[tr * 4 + 3][k];
            float b0 = Vt[tc * 4 + 0][k], b1 = Vt[tc * 4 + 1][k];
            float b2 = Vt[tc * 4 + 2][k], b3 = Vt[tc * 4 + 3][k];
            acc[0][0] += a0 * b0; acc[0][1] += a0 * b1; acc[0][2] += a0 * b2; acc[0][3] += a0 * b3;
            acc[1][0] += a1 * b0; acc[1][1] += a1 * b1; acc[1][2] += a1 * b2; acc[1][3] += a1 * b3;
            acc[2][0] += a2 * b0; acc[2][1] += a2 * b1; acc[2][2] += a2 * b2; acc[2][3] += a2 * b3;
            acc[3][0] += a3 * b0; acc[3][1] += a3 * b1; acc[3][2] += a3 * b2; acc[3][3] += a3 * b3;
        }
        __syncthreads();
    }
    #pragma unroll
    for (int i = 0; i < 4; i++)
        #pragma unroll
        for (int j = 0; j < 4; j++)
            atomicAdd(&KV[((size_t)b * Mm + tr * 4 + i) * Cc + cb + tc * 4 + j], acc[i][j]);
}

// ---------------- norm[b][n] = 1 / sum_m Qf[b,m,n]*(Ksum[b,m]+EPS) ----------------
__global__ __launch_bounds__(256) void norm_k(const float* __restrict__ Qf,
                                              const float* __restrict__ Ksum,
                                              float* __restrict__ normb) {
    int b = blockIdx.y;
    int n = blockIdx.x * 256 + threadIdx.x;
    __shared__ float ks[Mm];
    if (threadIdx.x < Mm) ks[threadIdx.x] = Ksum[b * Mm + threadIdx.x] + EPSf;
    __syncthreads();
    float s = 0.f;
    #pragma unroll 8
    for (int m = 0; m < Mm; m++) s += Qf[((size_t)b * Mm + m) * Nn + n] * ks[m];
    normb[(size_t)b * Nn + n] = 1.f / s;
}

// ---------------- out[b,c,n] = x + gamma * norm[b,n] * sum_m Qf[b,m,n]*KV[b,m,c] ----------------
__global__ __launch_bounds__(256) void final_k(const float* __restrict__ x,
                                               const float* __restrict__ Qf,
                                               const float* __restrict__ KV,
                                               const float* __restrict__ normb,
                                               const float* __restrict__ gamma,
                                               float* __restrict__ out) {
    const int nb = blockIdx.x * 64;
    const int cb = blockIdx.y * 64;
    const int b  = blockIdx.z;
    __shared__ float Qt[64][65];    // [m][n]
    __shared__ float KVt[64][65];   // [m][c]
    const int tid = threadIdx.x;
    const int tr = tid >> 4, tc = tid & 15;

    #pragma unroll
    for (int r = 0; r < 16; r++) {
        int m = (tid >> 6) + r * 4;
        int n = tid & 63;
        Qt[m][n]  = Qf[((size_t)b * Mm + m) * Nn + nb + n];
        KVt[m][n] = KV[((size_t)b * Mm + m) * Cc + cb + n];
    }
    __syncthreads();
    float acc[4][4] = {};
    #pragma unroll 8
    for (int k = 0; k < 64; k++) {
        float a0 = KVt[k][tr * 4 + 0], a1 = KVt[k][tr * 4 + 1];
        float a2 = KVt[k][tr * 4 + 2], a3 = KVt[k][tr * 4 + 3];
        float b0 = Qt[k][tc * 4 + 0], b1 = Qt[k][tc * 4 + 1];
        float b2 = Qt[k][tc * 4 + 2], b3 = Qt[k][tc * 4 + 3];
        acc[0][0] += a0 * b0; acc[0][1] += a0 * b1; acc[0][2] += a0 * b2; acc[0][3] += a0 * b3;
        acc[1][0] += a1 * b0; acc[1][1] += a1 * b1; acc[1][2] += a1 * b2; acc[1][3] += a1 * b3;
        acc[2][0] += a2 * b0; acc[2][1] += a2 * b1; acc[2][2] += a2 * b2; acc[2][3] += a2 * b3;
        acc[3][0] += a3 * b0; acc[3][1] += a3 * b1; acc[3][2] += a3 * b2; acc[3][3] += a3 * b3;
    }
    const float g = gamma[0];
    const int n0 = nb + tc * 4;
    float4 nrm = *(const float4*)(normb + (size_t)b * Nn + n0);
    #pragma unroll
    for (int i = 0; i < 4; i++) {
        int c = cb + tr * 4 + i;
        size_t idx = ((size_t)b * Cc + c) * Nn + n0;
        float4 xv = *(const float4*)(x + idx);
        float4 o;
        o.x = xv.x + g * nrm.x * acc[i][0];
        o.y = xv.y + g * nrm.y * acc[i][1];
        o.z = xv.z + g * nrm.z * acc[i][2];
        o.w = xv.w + g * nrm.w * acc[i][3];
        *(float4*)(out + idx) = o;
    }
}

extern "C" void kernel_launch(void* const* d_in, const int* in_sizes, int n_in,
                              void* d_out, int out_size, void* d_ws, size_t ws_size,
                              hipStream_t stream) {
    const float* x     = (const float*)d_in[0];
    const float* wq    = (const float*)d_in[1];
    const float* bq    = (const float*)d_in[2];
    const float* wk    = (const float*)d_in[3];
    const float* bk    = (const float*)d_in[4];
    const float* wv    = (const float*)d_in[5];
    const float* bv    = (const float*)d_in[6];
    const float* gamma = (const float*)d_in[7];
    float* out = (float*)d_out;
    float* ws  = (float*)d_ws;

    float*    gate  = ws + OFF_GATE;
    float*    bcat  = ws + OFF_BCAT;
    ushort_t* wbf   = (ushort_t*)(ws + OFF_WBF);
    ushort_t* xT    = (ushort_t*)(ws + OFF_XT);
    float*    Qf    = ws + OFF_QF;
    float*    Kf    = ws + OFF_KF;
    ushort_t* Vbf   = (ushort_t*)(ws + OFF_VBF);
    float*    KV    = ws + OFF_KV;
    float*    Ksum  = ws + OFF_KSUM;
    float*    normb = ws + OFF_NORM;

    wconv_k<<<(OC * Cc + 255) / 256, 256, 0, stream>>>(wq, bq, wk, bk, wv, bv, wbf, bcat);
    xtrans_k<<<dim3(Nn / 64, Cc / 64, Bb), 256, 0, stream>>>(x, xT);
    gate_k<<<Bb * Cc, 256, 0, stream>>>(x, gate);
    qkv_mfma_k<<<dim3(Nn / 128, OC / 128, Bb), 256, 0, stream>>>(wbf, xT, bcat, gate, Qf, Kf, Vbf);
    ksum_k<<<Bb * Mm, 256, 0, stream>>>(Kf, Ksum);
    hipMemsetAsync(KV, 0, (size_t)Bb * Mm * Cc * sizeof(float), stream);
    kv_k<<<dim3(Cc / 64, Nn / 512, Bb), 256, 0, stream>>>(Kf, Vbf, KV);
    norm_k<<<dim3(Nn / 256, Bb), 256, 0, stream>>>(Qf, Ksum, normb);
    final_k<<<dim3(Nn / 64, Cc / 64, Bb), 256, 0, stream>>>(x, Qf, KV, normb, gamma, out);
}

// Round 3
// 158.366 us; speedup vs baseline: 3.4439x; 1.4315x over previous
//
#include <hip/hip_runtime.h>
#include <math.h>

#define Bb 8
#define Cc 512
#define Nn 4096
#define Mm 64
#define OC 640            // M + M + C
#define EPSf 1e-6f

typedef unsigned short ushort_t;
typedef unsigned int uint_t;
typedef __attribute__((ext_vector_type(8))) short short8;
typedef __attribute__((ext_vector_type(4))) float f32x4;

// ---------------- workspace layout (float slots) ----------------
constexpr size_t OFF_GATE = 0;                                   // [B][C] f32
constexpr size_t OFF_BCAT = OFF_GATE + (size_t)Bb * Cc;          // [OC] f32
constexpr size_t OFF_GPM  = OFF_BCAT + (size_t)OC;               // [64][B*C] gate max partials
constexpr size_t OFF_GPS  = OFF_GPM + (size_t)64 * Bb * Cc;      // [64][B*C] gate sum partials
constexpr size_t OFF_WBF  = OFF_GPS + (size_t)64 * Bb * Cc;      // [OC][C] bf16
constexpr size_t OFF_XT   = OFF_WBF + (size_t)OC * Cc / 2;       // [B][N][C] bf16 (later reused as KVpart [8][B][C][M] f32 = 8MB < 33.5MB)
constexpr size_t OFF_QF   = OFF_XT + (size_t)Bb * Nn * Cc / 2;   // [B][M][N] f32
constexpr size_t OFF_KBF  = OFF_QF + (size_t)Bb * Mm * Nn;       // [B][M][N] bf16
constexpr size_t OFF_VBF  = OFF_KBF + (size_t)Bb * Mm * Nn / 2;  // [B][C][N] bf16
constexpr size_t OFF_KVT  = OFF_VBF + (size_t)Bb * Cc * Nn / 2;  // [B][C][M] f32 (KV transposed)
constexpr size_t OFF_KSUM = OFF_KVT + (size_t)Bb * Cc * Mm;      // [B][M]
constexpr size_t OFF_NORM = OFF_KSUM + (size_t)Bb * Mm;          // [B][N]

__device__ __forceinline__ float softplus_f(float v) {
    return (v > 20.f) ? v : log1pf(expf(v));
}
__device__ __forceinline__ ushort_t f2bf(float f) {
    uint_t u = __float_as_uint(f);
    uint_t r = (u + 0x7fffu + ((u >> 16) & 1u)) >> 16;
    return (ushort_t)r;
}
__device__ __forceinline__ float bf2f(ushort_t h) {
    return __uint_as_float(((uint_t)h) << 16);
}
__device__ __forceinline__ void gload_lds16(const void* g, void* l) {
    __builtin_amdgcn_global_load_lds(
        (const __attribute__((address_space(1))) unsigned int*)g,
        (__attribute__((address_space(3))) unsigned int*)l, 16, 0, 0);
}

// ---------------- weight concat + bf16 convert ----------------
__global__ void wconv_k(const float* __restrict__ wq, const float* __restrict__ bq,
                        const float* __restrict__ wk, const float* __restrict__ bk,
                        const float* __restrict__ wv, const float* __restrict__ bv,
                        ushort_t* __restrict__ wbf, float* __restrict__ bcat) {
    int i = blockIdx.x * 256 + threadIdx.x;
    if (i < OC * Cc) {
        int o = i / Cc, c = i % Cc;
        float v;
        if (o < Mm)            v = wq[o * Cc + c];
        else if (o < 2 * Mm)   v = wk[(o - Mm) * Cc + c];
        else                   v = wv[(o - 2 * Mm) * Cc + c];
        wbf[i] = f2bf(v);
    }
    if (i < OC) {
        float v;
        if (i < Mm)            v = bq[i];
        else if (i < 2 * Mm)   v = bk[i - Mm];
        else                   v = bv[i - 2 * Mm];
        bcat[i] = v;
    }
}

// ---------------- transpose+convert + gate partials ----------------
// xT[b][n][c] = bf16(x[b][c][n]); gpm/gps[nb][b*C+c] = max/sum over this 64-n tile.
// grid: (N/64, C/64, B), block 256
__global__ __launch_bounds__(256) void xtrans_k(const float* __restrict__ x, ushort_t* __restrict__ xT,
                                                float* __restrict__ gpm, float* __restrict__ gps) {
    const int nb = blockIdx.x * 64;
    const int cb = blockIdx.y * 64;
    const int b  = blockIdx.z;
    __shared__ float Xt[64][65];
    __shared__ float pmx[4][64], psm[4][64];
    const int t = threadIdx.x;
    #pragma unroll
    for (int r = 0; r < 16; r++) {
        int cl = (t >> 6) + r * 4;
        int nl = t & 63;
        Xt[cl][nl] = x[((size_t)b * Cc + cb + cl) * Nn + nb + nl];
    }
    __syncthreads();
    #pragma unroll
    for (int r = 0; r < 8; r++) {
        int nl = (t >> 5) + r * 8;
        int c0 = (t & 31) * 2;
        uint_t pk = (uint_t)f2bf(Xt[c0][nl]) | ((uint_t)f2bf(Xt[c0 + 1][nl]) << 16);
        *(uint_t*)(xT + ((size_t)b * Nn + nb + nl) * Cc + cb + c0) = pk;
    }
    // gate partials: per c row, max+sum over 64 n of this tile
    {
        int cl = t & 63, q = t >> 6;
        float mx = -3.4e38f, sm = 0.f;
        #pragma unroll
        for (int j = 0; j < 16; j++) {
            float v = Xt[cl][q * 16 + j];
            mx = fmaxf(mx, v); sm += v;
        }
        pmx[q][cl] = mx; psm[q][cl] = sm;
    }
    __syncthreads();
    if (t < 64) {
        float mx = fmaxf(fmaxf(pmx[0][t], pmx[1][t]), fmaxf(pmx[2][t], pmx[3][t]));
        float sm = psm[0][t] + psm[1][t] + psm[2][t] + psm[3][t];
        size_t idx = (size_t)blockIdx.x * (Bb * Cc) + (size_t)b * Cc + cb + t;
        gpm[idx] = mx;
        gps[idx] = sm;
    }
}

// ---------------- gate reduce: gate[bc] = max + mean over 64 tiles ----------------
__global__ void gatered_k(const float* __restrict__ gpm, const float* __restrict__ gps,
                          float* __restrict__ gate) {
    int bc = blockIdx.x;
    int l = threadIdx.x;  // 64 threads
    float mx = gpm[(size_t)l * (Bb * Cc) + bc];
    float sm = gps[(size_t)l * (Bb * Cc) + bc];
    #pragma unroll
    for (int off = 32; off; off >>= 1) {
        mx = fmaxf(mx, __shfl_xor(mx, off));
        sm += __shfl_xor(sm, off);
    }
    if (l == 0) gate[bc] = mx + sm * (1.f / Nn);
}

// ---------------- fused QKV GEMM via MFMA bf16, double-buffered ----------------
// grid: (N/128, OC/128, B), block 256 (4 waves, 2x2 of 64x64 sub-tiles), BK=32.
__global__ __launch_bounds__(256, 2) void qkv_mfma_k(const ushort_t* __restrict__ wbf,
                                                     const ushort_t* __restrict__ xT,
                                                     const float* __restrict__ bcat,
                                                     const float* __restrict__ gate,
                                                     float* __restrict__ Qf,
                                                     ushort_t* __restrict__ Kbf,
                                                     ushort_t* __restrict__ Vbf) {
    const int nb = blockIdx.x * 128;
    const int ob = blockIdx.y * 128;
    const int b  = blockIdx.z;
    __shared__ ushort_t At[2][128 * 32];
    __shared__ ushort_t Bt[2][128 * 32];
    const int tid  = threadIdx.x;
    const int w    = tid >> 6;
    const int lane = tid & 63;
    const int wr   = w >> 1, wc = w & 1;
    const int hi   = lane >> 4, lo = lane & 15;
    const int rwl  = lane >> 2;
    const int kc   = (lane & 3) * 8;
    const ushort_t* xb = xT + (size_t)b * Nn * Cc;

    f32x4 acc[4][4] = {};

    auto stage = [&](int buf, int kb) {
        #pragma unroll
        for (int li = 0; li < 2; li++) {
            const int rw = (w * 2 + li) * 16 + rwl;
            gload_lds16(wbf + (size_t)(ob + rw) * Cc + kb + kc, &At[buf][(w * 2 + li) * 512]);
            gload_lds16(xb + (size_t)(nb + rw) * Cc + kb + kc, &Bt[buf][(w * 2 + li) * 512]);
        }
    };
    auto compute = [&](int buf) {
        short8 a[4], bfr[4];
        #pragma unroll
        for (int mi = 0; mi < 4; mi++)
            a[mi] = *(const short8*)(&At[buf][(wr * 64 + mi * 16 + lo) * 32 + hi * 8]);
        #pragma unroll
        for (int ni = 0; ni < 4; ni++)
            bfr[ni] = *(const short8*)(&Bt[buf][(wc * 64 + ni * 16 + lo) * 32 + hi * 8]);
        #pragma unroll
        for (int mi = 0; mi < 4; mi++)
            #pragma unroll
            for (int ni = 0; ni < 4; ni++)
                acc[mi][ni] = __builtin_amdgcn_mfma_f32_16x16x32_bf16(a[mi], bfr[ni], acc[mi][ni], 0, 0, 0);
    };

    stage(0, 0);
    __syncthreads();
    int cur = 0;
    for (int t = 0; t < 15; t++) {
        stage(cur ^ 1, (t + 1) * 32);
        compute(cur);
        __syncthreads();
        cur ^= 1;
    }
    compute(cur);

    #pragma unroll
    for (int mi = 0; mi < 4; mi++) {
        #pragma unroll
        for (int r = 0; r < 4; r++) {
            const int o = ob + wr * 64 + mi * 16 + hi * 4 + r;
            const float bias = bcat[o];
            if (o < Mm) {
                float* dst = Qf + ((size_t)b * Mm + o) * Nn;
                #pragma unroll
                for (int ni = 0; ni < 4; ni++)
                    dst[nb + wc * 64 + ni * 16 + lo] = softplus_f(acc[mi][ni][r] + bias);
            } else if (o < 2 * Mm) {
                ushort_t* dst = Kbf + ((size_t)b * Mm + (o - Mm)) * Nn;
                #pragma unroll
                for (int ni = 0; ni < 4; ni++)
                    dst[nb + wc * 64 + ni * 16 + lo] = f2bf(softplus_f(acc[mi][ni][r] + bias));
            } else {
                const int c = o - 2 * Mm;
                const float g = gate[b * Cc + c];
                ushort_t* dst = Vbf + ((size_t)b * Cc + c) * Nn;
                #pragma unroll
                for (int ni = 0; ni < 4; ni++)
                    dst[nb + wc * 64 + ni * 16 + lo] = f2bf(g * (acc[mi][ni][r] + bias));
            }
        }
    }
}

// ---------------- Ksum[b][m] = sum_n Kbf ----------------
__global__ __launch_bounds__(256) void ksum_k(const ushort_t* __restrict__ Kbf, float* __restrict__ Ksum) {
    int bm = blockIdx.x;
    const ushort_t* row = Kbf + (size_t)bm * Nn;
    int t = threadIdx.x;
    float sm = 0.f;
    for (int i = t * 8; i < Nn; i += 2048) {
        short8 v = *(const short8*)(row + i);
        #pragma unroll
        for (int j = 0; j < 8; j++) sm += bf2f((ushort_t)v[j]);
    }
    #pragma unroll
    for (int off = 32; off; off >>= 1) sm += __shfl_xor(sm, off);
    __shared__ float ssm[4];
    if ((t & 63) == 0) ssm[t >> 6] = sm;
    __syncthreads();
    if (t == 0) Ksum[bm] = ssm[0] + ssm[1] + ssm[2] + ssm[3];
}

// ---------------- KVpart[s][b][c][m] = sum_{n in split} V[b,c,n]*K[b,m,n] via MFMA ----------------
// grid: (C/128, 8 splits, B), block 256, BK=32, double-buffered.
__global__ __launch_bounds__(256, 2) void kv_mfma_k(const ushort_t* __restrict__ Kbf,
                                                    const ushort_t* __restrict__ Vbf,
                                                    float* __restrict__ KVpart) {
    const int cb = blockIdx.x * 128;
    const int split = blockIdx.y;
    const int b = blockIdx.z;
    __shared__ ushort_t Vt[2][128 * 32];
    __shared__ ushort_t Kt[2][64 * 32];
    const int tid = threadIdx.x;
    const int w = tid >> 6, lane = tid & 63;
    const int hi = lane >> 4, lo = lane & 15;
    const int rwl = lane >> 2, kc = (lane & 3) * 8;
    const ushort_t* Vb = Vbf + (size_t)b * Cc * Nn;
    const ushort_t* Kb = Kbf + (size_t)b * Mm * Nn;
    const int nbase = split * 512;

    f32x4 acc[2][4] = {};

    auto stage = [&](int buf, int n0) {
        #pragma unroll
        for (int li = 0; li < 2; li++) {
            const int rw = (w * 2 + li) * 16 + rwl;
            gload_lds16(Vb + (size_t)(cb + rw) * Nn + n0 + kc, &Vt[buf][(w * 2 + li) * 512]);
        }
        gload_lds16(Kb + (size_t)(w * 16 + rwl) * Nn + n0 + kc, &Kt[buf][w * 512]);
    };
    auto compute = [&](int buf) {
        short8 a[2], bv[4];
        #pragma unroll
        for (int mi = 0; mi < 2; mi++)
            a[mi] = *(const short8*)(&Vt[buf][(w * 32 + mi * 16 + lo) * 32 + hi * 8]);
        #pragma unroll
        for (int ni = 0; ni < 4; ni++)
            bv[ni] = *(const short8*)(&Kt[buf][(ni * 16 + lo) * 32 + hi * 8]);
        #pragma unroll
        for (int mi = 0; mi < 2; mi++)
            #pragma unroll
            for (int ni = 0; ni < 4; ni++)
                acc[mi][ni] = __builtin_amdgcn_mfma_f32_16x16x32_bf16(a[mi], bv[ni], acc[mi][ni], 0, 0, 0);
    };

    stage(0, nbase);
    __syncthreads();
    int cur = 0;
    for (int t = 0; t < 15; t++) {
        stage(cur ^ 1, nbase + (t + 1) * 32);
        compute(cur);
        __syncthreads();
        cur ^= 1;
    }
    compute(cur);

    float* dst = KVpart + (size_t)(split * Bb + b) * Cc * Mm;
    #pragma unroll
    for (int mi = 0; mi < 2; mi++)
        #pragma unroll
        for (int r = 0; r < 4; r++) {
            const int c = cb + w * 32 + mi * 16 + hi * 4 + r;
            #pragma unroll
            for (int ni = 0; ni < 4; ni++)
                dst[(size_t)c * Mm + ni * 16 + lo] = acc[mi][ni][r];
        }
}

// ---------------- KVT[b][c][m] = sum over 8 splits ----------------
__global__ __launch_bounds__(256) void kvred_k(const float* __restrict__ KVpart, float* __restrict__ KVT) {
    int i = blockIdx.x * 256 + threadIdx.x;  // float4 index; total B*C*M/4 = 65536
    const f32x4* p = (const f32x4*)KVpart;
    f32x4 s = p[i];
    #pragma unroll
    for (int sp = 1; sp < 8; sp++) s += p[(size_t)sp * 65536 + i];
    ((f32x4*)KVT)[i] = s;
}

// ---------------- norm[b][n] = 1 / sum_m Qf[b,m,n]*(Ksum[b,m]+EPS) ----------------
__global__ __launch_bounds__(256) void norm_k(const float* __restrict__ Qf,
                                              const float* __restrict__ Ksum,
                                              float* __restrict__ normb) {
    int b = blockIdx.y;
    int n = blockIdx.x * 256 + threadIdx.x;
    __shared__ float ks[Mm];
    if (threadIdx.x < Mm) ks[threadIdx.x] = Ksum[b * Mm + threadIdx.x] + EPSf;
    __syncthreads();
    float s = 0.f;
    #pragma unroll 8
    for (int m = 0; m < Mm; m++) s += Qf[((size_t)b * Mm + m) * Nn + n] * ks[m];
    normb[(size_t)b * Nn + n] = 1.f / s;
}

// ---------------- out[b,c,n] = x + gamma * norm[b,n] * sum_m Qf[b,m,n]*KVT[b,c,m] ----------------
__global__ __launch_bounds__(256) void final_k(const float* __restrict__ x,
                                               const float* __restrict__ Qf,
                                               const float* __restrict__ KVT,
                                               const float* __restrict__ normb,
                                               const float* __restrict__ gamma,
                                               float* __restrict__ out) {
    const int nb = blockIdx.x * 64;
    const int cb = blockIdx.y * 64;
    const int b  = blockIdx.z;
    __shared__ float Qt[64][65];    // [m][n]
    __shared__ float KVt[64][65];   // [m][c]
    const int tid = threadIdx.x;
    const int tr = tid >> 4, tc = tid & 15;

    #pragma unroll
    for (int r = 0; r < 16; r++) {
        int a = (tid >> 6) + r * 4;   // m for Qt, c for KVt
        int bl = tid & 63;            // n for Qt, m for KVt
        Qt[a][bl]  = Qf[((size_t)b * Mm + a) * Nn + nb + bl];
        KVt[bl][a] = KVT[((size_t)b * Cc + cb + a) * Mm + bl];
    }
    __syncthreads();
    float acc[4][4] = {};
    #pragma unroll 8
    for (int k = 0; k < 64; k++) {
        float a0 = KVt[k][tr * 4 + 0], a1 = KVt[k][tr * 4 + 1];
        float a2 = KVt[k][tr * 4 + 2], a3 = KVt[k][tr * 4 + 3];
        float b0 = Qt[k][tc * 4 + 0], b1 = Qt[k][tc * 4 + 1];
        float b2 = Qt[k][tc * 4 + 2], b3 = Qt[k][tc * 4 + 3];
        acc[0][0] += a0 * b0; acc[0][1] += a0 * b1; acc[0][2] += a0 * b2; acc[0][3] += a0 * b3;
        acc[1][0] += a1 * b0; acc[1][1] += a1 * b1; acc[1][2] += a1 * b2; acc[1][3] += a1 * b3;
        acc[2][0] += a2 * b0; acc[2][1] += a2 * b1; acc[2][2] += a2 * b2; acc[2][3] += a2 * b3;
        acc[3][0] += a3 * b0; acc[3][1] += a3 * b1; acc[3][2] += a3 * b2; acc[3][3] += a3 * b3;
    }
    const float g = gamma[0];
    const int n0 = nb + tc * 4;
    float4 nrm = *(const float4*)(normb + (size_t)b * Nn + n0);
    #pragma unroll
    for (int i = 0; i < 4; i++) {
        int c = cb + tr * 4 + i;
        size_t idx = ((size_t)b * Cc + c) * Nn + n0;
        float4 xv = *(const float4*)(x + idx);
        float4 o;
        o.x = xv.x + g * nrm.x * acc[i][0];
        o.y = xv.y + g * nrm.y * acc[i][1];
        o.z = xv.z + g * nrm.z * acc[i][2];
        o.w = xv.w + g * nrm.w * acc[i][3];
        *(float4*)(out + idx) = o;
    }
}

extern "C" void kernel_launch(void* const* d_in, const int* in_sizes, int n_in,
                              void* d_out, int out_size, void* d_ws, size_t ws_size,
                              hipStream_t stream) {
    const float* x     = (const float*)d_in[0];
    const float* wq    = (const float*)d_in[1];
    const float* bq    = (const float*)d_in[2];
    const float* wk    = (const float*)d_in[3];
    const float* bk    = (const float*)d_in[4];
    const float* wv    = (const float*)d_in[5];
    const float* bv    = (const float*)d_in[6];
    const float* gamma = (const float*)d_in[7];
    float* out = (float*)d_out;
    float* ws  = (float*)d_ws;

    float*    gate   = ws + OFF_GATE;
    float*    bcat   = ws + OFF_BCAT;
    float*    gpm    = ws + OFF_GPM;
    float*    gps    = ws + OFF_GPS;
    ushort_t* wbf    = (ushort_t*)(ws + OFF_WBF);
    ushort_t* xT     = (ushort_t*)(ws + OFF_XT);
    float*    KVpart = ws + OFF_XT;   // aliases xT (dead after qkv)
    float*    Qf     = ws + OFF_QF;
    ushort_t* Kbf    = (ushort_t*)(ws + OFF_KBF);
    ushort_t* Vbf    = (ushort_t*)(ws + OFF_VBF);
    float*    KVT    = ws + OFF_KVT;
    float*    Ksum   = ws + OFF_KSUM;
    float*    normb  = ws + OFF_NORM;

    wconv_k<<<(OC * Cc + 255) / 256, 256, 0, stream>>>(wq, bq, wk, bk, wv, bv, wbf, bcat);
    xtrans_k<<<dim3(Nn / 64, Cc / 64, Bb), 256, 0, stream>>>(x, xT, gpm, gps);
    gatered_k<<<Bb * Cc, 64, 0, stream>>>(gpm, gps, gate);
    qkv_mfma_k<<<dim3(Nn / 128, OC / 128, Bb), 256, 0, stream>>>(wbf, xT, bcat, gate, Qf, Kbf, Vbf);
    ksum_k<<<Bb * Mm, 256, 0, stream>>>(Kbf, Ksum);
    kv_mfma_k<<<dim3(Cc / 128, 8, Bb), 256, 0, stream>>>(Kbf, Vbf, KVpart);
    kvred_k<<<(Bb * Cc * Mm / 4) / 256, 256, 0, stream>>>(KVpart, KVT);
    norm_k<<<dim3(Nn / 256, Bb), 256, 0, stream>>>(Qf, Ksum, normb);
    final_k<<<dim3(Nn / 64, Cc / 64, Bb), 256, 0, stream>>>(x, Qf, KVT, normb, gamma, out);
}